// Round 8
// baseline (239.523 us; speedup 1.0000x reference)
//
#include <hip/hip_runtime.h>
#include <math.h>

#define BB 8
#define CH 128
#define HH 64
#define WWID 64
#define HIN 62
#define WIN 62
#define SPIN (HIN*WIN)      // 3844
#define HP 66
#define WP 66
#define GG 4
#define GCH 32
#define NPIX (BB*HH*WWID)   // 32768
#define ASTRIDE 136         // LDS A-tile row stride in halfs

typedef _Float16 v8h __attribute__((ext_vector_type(8)));
typedef _Float16 v4h __attribute__((ext_vector_type(4)));
typedef float    v4f __attribute__((ext_vector_type(4)));
typedef float    f4a __attribute__((ext_vector_type(4), aligned(4)));  // 4B-aligned float4 load

// ---- P0: pack 4 weight mats into MFMA B-frag order (f16) + dwT transpose ---
__global__ __launch_bounds__(256) void p0_pack(const float* __restrict__ conv_w,
                                               const float* __restrict__ in_proj_w,
                                               const float* __restrict__ off_w,
                                               const float* __restrict__ mask_w,
                                               const float* __restrict__ out_proj_w,
                                               const float* __restrict__ dw_w,
                                               _Float16* __restrict__ wp,
                                               float* __restrict__ dwT) {
    int t = threadIdx.x;
    if (blockIdx.x == 31) {                         // dwT[tap][c] transpose
        if (t < 128) {
            #pragma unroll
            for (int tap = 0; tap < 9; tap++) dwT[tap * 128 + t] = dw_w[t * 9 + tap];
        }
        return;
    }
    int tid = blockIdx.x * 256 + t;                 // 0..7935
    int mat, base;
    if (tid < 2048)      { mat = 0; base = 0; }
    else if (tid < 4096) { mat = 1; base = 2048; }
    else if (tid < 5888) { mat = 2; base = 4096; }
    else                 { mat = 3; base = 5888; }
    int fi = tid - base;
    int nt = fi >> 8, rem = fi & 255, kc = rem >> 6, lane = rem & 63;
    int n = nt * 16 + (lane & 15);
    int kbase = kc * 32 + ((lane >> 4) & 3) * 8;
    _Float16* dst = wp + (size_t)tid * 8;
    #pragma unroll
    for (int j = 0; j < 8; j++) {
        int k = kbase + j;
        float v;
        if (mat == 0)      v = conv_w[n * CH + k];
        else if (mat == 1) v = in_proj_w[k * CH + n];
        else if (mat == 2) v = (n < 72) ? off_w[k * 72 + n]
                               : (n < 108 ? mask_w[k * 36 + (n - 72)] : 0.f);
        else               v = out_proj_w[k * CH + n];
        dst[j] = (_Float16)v;
    }
}

// ---- MFMA core, 8-wave split: wave wv -> m-tile wv>>1, nt base (wv&1)*4 ----
__device__ inline void mfma_loop8(const _Float16* __restrict__ a16,
                                  const _Float16* __restrict__ wp,
                                  v4f acc[4], int t) {
    int lane = t & 63;
    int wv = t >> 6;                                // 0..7
    int mt = wv >> 1, ntb = (wv & 1) * 4;
    const _Float16* abase = a16 + (mt * 16 + (lane & 15)) * ASTRIDE + ((lane >> 4) * 8);
    #pragma unroll
    for (int kc = 0; kc < 4; kc++) {
        v8h av = *(const v8h*)(abase + kc * 32);
        #pragma unroll
        for (int j = 0; j < 4; j++) {
            v8h bv = *(const v8h*)(wp + ((size_t)((ntb + j) * 4 + kc) * 64 + lane) * 8);
            acc[j] = __builtin_amdgcn_mfma_f32_16x16x32_f16(av, bv, acc[j], 0, 0, 0);
        }
    }
}

// write fp32 C-layout accs into a16 as f16 [px][c] (this wave's nt-half)
__device__ inline void acc_to_a16_8(_Float16* a16, v4f acc[4], int t) {
    int lane = t & 63, ncol = lane & 15;
    int wv = t >> 6;
    int m0 = (wv >> 1) * 16 + ((lane >> 4) * 4);
    int ntb = (wv & 1) * 4;
    #pragma unroll
    for (int j = 0; j < 4; j++)
        #pragma unroll
        for (int r = 0; r < 4; r++)
            a16[(m0 + r) * ASTRIDE + (ntb + j) * 16 + ncol] = (_Float16)acc[j][r];
}

// ---- gA: fused conv1x1(pad=1) + in_proj, all-MFMA; emits y16 + xpad16 ------
__global__ __launch_bounds__(512) void gA_conv_inproj(const float* __restrict__ x,
                                                      const _Float16* __restrict__ wp_conv,
                                                      const _Float16* __restrict__ wp_in,
                                                      const float* __restrict__ conv_b,
                                                      const float* __restrict__ in_b,
                                                      _Float16* __restrict__ y16,
                                                      _Float16* __restrict__ xpad16) {
    __shared__ _Float16 a16[64 * ASTRIDE];
    int pix0 = blockIdx.x * 64;                     // one row
    int t = threadIdx.x;
    int h = (pix0 >> 6) & 63, b = pix0 >> 12;
    bool hin = (h >= 1 && h <= 62);
    // vectorized stage: 4 w-values per thread-iter via (possibly unaligned) float4
    for (int q = t; q < 2048; q += 512) {
        int c = q >> 4, w4 = (q & 15) * 4;
        float4 v = make_float4(0.f, 0.f, 0.f, 0.f);
        if (hin) {
            const float* xr = x + ((size_t)(b * CH + c)) * SPIN + (h - 1) * WIN;
            if (w4 == 0)       { f4a e = *(const f4a*)&xr[0];      v = make_float4(0.f, e[0], e[1], e[2]); }
            else if (w4 == 60) { f4a e = *(const f4a*)&xr[58];     v = make_float4(e[1], e[2], e[3], 0.f); }
            else               { f4a e = *(const f4a*)&xr[w4 - 1]; v = make_float4(e[0], e[1], e[2], e[3]); }
        }
        a16[(w4 + 0) * ASTRIDE + c] = (_Float16)v.x;
        a16[(w4 + 1) * ASTRIDE + c] = (_Float16)v.y;
        a16[(w4 + 2) * ASTRIDE + c] = (_Float16)v.z;
        a16[(w4 + 3) * ASTRIDE + c] = (_Float16)v.w;
    }
    __syncthreads();
    int lane = t & 63, ncol = lane & 15;
    int ntb = ((t >> 6) & 1) * 4;
    v4f acc[4];
    #pragma unroll
    for (int j = 0; j < 4; j++) {
        float bv = conv_b[(ntb + j) * 16 + ncol];
        acc[j] = (v4f){bv, bv, bv, bv};
    }
    mfma_loop8(a16, wp_conv, acc, t);
    __syncthreads();                                // x-tile reads done
    acc_to_a16_8(a16, acc, t);                      // a16 = y tile (f16)
    __syncthreads();
    {
        _Float16* dst = y16 + (size_t)pix0 * CH;
        for (int q = t; q < 1024; q += 512)
            *(v8h*)&dst[q * 8] = *(const v8h*)&a16[(q >> 4) * ASTRIDE + (q & 15) * 8];
    }
    v4f acc2[4];
    #pragma unroll
    for (int j = 0; j < 4; j++) {
        float bv = in_b[(ntb + j) * 16 + ncol];
        acc2[j] = (v4f){bv, bv, bv, bv};
    }
    mfma_loop8(a16, wp_in, acc2, t);
    __syncthreads();                                // y-tile reads done
    acc_to_a16_8(a16, acc2, t);                     // a16 = x_proj tile (f16)
    __syncthreads();
    {
        _Float16* dst = xpad16 + (size_t)(((b * HP) + h + 1) * WP + 1) * CH;
        for (int q = t; q < 1024; q += 512)
            *(v8h*)&dst[q * 8] = *(const v8h*)&a16[(q >> 4) * ASTRIDE + (q & 15) * 8];
    }
}

// ---- gF: fused dw3x3 + LN + GELU + off/mask MFMA + softmax + taps ----------
__global__ __launch_bounds__(512) void gF_dwln_offmask(const _Float16* __restrict__ y16,
                                                       const _Float16* __restrict__ wp_om,
                                                       const float* __restrict__ dwT,
                                                       const float* __restrict__ dw_b,
                                                       const float* __restrict__ ln_g,
                                                       const float* __restrict__ ln_b,
                                                       const float* __restrict__ off_b,
                                                       const float* __restrict__ mask_b,
                                                       float* __restrict__ tapmeta) {
    __shared__ char smem[49920];
    _Float16* ylds = (_Float16*)smem;               // v8h idx: (r*16+c8)*65 + w
    int t = threadIdx.x;
    int pix0 = blockIdx.x * 64;
    int h = (pix0 >> 6) & 63, b = pix0 >> 12;
    if (h == 0 || h == 63) {
        for (int i = t; i < 3120; i += 512) *(v8h*)&ylds[i * 8] = (v8h)(_Float16)0;
        __syncthreads();
    }
    for (int idx = t; idx < 3072; idx += 512) {
        int r = idx >> 10, w = (idx >> 4) & 63, c8 = idx & 15;
        int hh = h + r - 1;
        if (hh >= 0 && hh <= 63) {
            v8h v = *(const v8h*)&y16[(size_t)(((b * 64 + hh) * 64 + w) * CH) + c8 * 8];
            *(v8h*)&ylds[(size_t)((r * 16 + c8) * 65 + w) * 8] = v;
        }
    }
    __syncthreads();
    int px = t >> 3, q8 = t & 7;
    float acc[16];
    #pragma unroll
    for (int cb = 0; cb < 4; cb++) *(float4*)&acc[cb * 4] = *(const float4*)&dw_b[q8 * 16 + cb * 4];
    #pragma unroll
    for (int r = 0; r < 3; r++) {
        #pragma unroll
        for (int kx = 0; kx < 3; kx++) {
            int wq = px + kx - 1;
            bool valid = (wq >= 0 && wq <= 63);
            int wpc = min(max(wq, 0), 63);
            int tap = r * 3 + kx;
            if (valid) {
                #pragma unroll
                for (int cb = 0; cb < 2; cb++) {
                    v8h yv = *(const v8h*)&ylds[(size_t)((r * 16 + q8 * 2 + cb) * 65 + wpc) * 8];
                    float4 wa = *(const float4*)&dwT[tap * 128 + q8 * 16 + cb * 8];
                    float4 wb = *(const float4*)&dwT[tap * 128 + q8 * 16 + cb * 8 + 4];
                    acc[cb*8+0] += (float)yv[0] * wa.x; acc[cb*8+1] += (float)yv[1] * wa.y;
                    acc[cb*8+2] += (float)yv[2] * wa.z; acc[cb*8+3] += (float)yv[3] * wa.w;
                    acc[cb*8+4] += (float)yv[4] * wb.x; acc[cb*8+5] += (float)yv[5] * wb.y;
                    acc[cb*8+6] += (float)yv[6] * wb.z; acc[cb*8+7] += (float)yv[7] * wb.w;
                }
            }
        }
    }
    float s = 0.f, ss = 0.f;
    #pragma unroll
    for (int j = 0; j < 16; j++) { s += acc[j]; ss += acc[j] * acc[j]; }
    s  += __shfl_xor(s, 1);  s  += __shfl_xor(s, 2);  s  += __shfl_xor(s, 4);
    ss += __shfl_xor(ss, 1); ss += __shfl_xor(ss, 2); ss += __shfl_xor(ss, 4);
    float mu = s * (1.f / 128.f);
    float var = ss * (1.f / 128.f) - mu * mu;
    float rstd = rsqrtf(var + 1e-5f);
    v8h dreg[2];
    #pragma unroll
    for (int cb = 0; cb < 2; cb++) {
        float4 ga = *(const float4*)&ln_g[q8 * 16 + cb * 8];
        float4 gb = *(const float4*)&ln_g[q8 * 16 + cb * 8 + 4];
        float4 ba = *(const float4*)&ln_b[q8 * 16 + cb * 8];
        float4 bb = *(const float4*)&ln_b[q8 * 16 + cb * 8 + 4];
        float gv[8] = {ga.x, ga.y, ga.z, ga.w, gb.x, gb.y, gb.z, gb.w};
        float bv[8] = {ba.x, ba.y, ba.z, ba.w, bb.x, bb.y, bb.z, bb.w};
        #pragma unroll
        for (int j = 0; j < 8; j++) {
            float xln = (acc[cb * 8 + j] - mu) * rstd * gv[j] + bv[j];
            float gel = 0.5f * xln * (1.f + erff(xln * 0.70710678118654752f));
            dreg[cb][j] = (_Float16)gel;
        }
    }
    __syncthreads();                                // ylds dead
    _Float16* a16 = (_Float16*)smem;
    float* om = (float*)(smem + 17408);
    #pragma unroll
    for (int cb = 0; cb < 2; cb++)
        *(v8h*)&a16[px * ASTRIDE + q8 * 16 + cb * 8] = dreg[cb];
    __syncthreads();
    int lane = t & 63, ncol = lane & 15;
    int ntb = ((t >> 6) & 1) * 4;
    v4f macc[4];
    #pragma unroll
    for (int j = 0; j < 4; j++) {
        int n = (ntb + j) * 16 + ncol;
        float bv = (n < 72) ? off_b[n] : (n < 108 ? mask_b[n - 72] : 0.f);
        macc[j] = (v4f){bv, bv, bv, bv};
    }
    mfma_loop8(a16, wp_om, macc, t);
    int m0 = ((t >> 6) >> 1) * 16 + ((lane >> 4) * 4);
    #pragma unroll
    for (int j = 0; j < 4; j++) {
        if (ntb + j < 7) {
            #pragma unroll
            for (int r = 0; r < 4; r++)
                om[(m0 + r) * 112 + (ntb + j) * 16 + ncol] = macc[j][r];
        }
    }
    __syncthreads();
    if (t < 256) {
        int pxs = t >> 2, gx = t & 3;
        const float* row = &om[pxs * 112];
        float lg[9];
        #pragma unroll
        for (int i = 0; i < 9; i++) lg[i] = row[72 + gx * 9 + i];
        float mx = lg[0];
        #pragma unroll
        for (int i = 1; i < 9; i++) mx = fmaxf(mx, lg[i]);
        float e[9], sum = 0.f;
        #pragma unroll
        for (int i = 0; i < 9; i++) { e[i] = expf(lg[i] - mx); sum += e[i]; }
        float inv = 1.f / sum;
        float* tm = tapmeta + ((size_t)(pix0 + pxs) * 36 + gx * 9) * 8;
        #pragma unroll
        for (int p = 0; p < 9; p++) {
            int gp = gx * 9 + p;
            float offx = row[gp * 2];
            float offy = row[gp * 2 + 1];
            float m = e[p] * inv;
            float ix = (float)(pxs + (p / 3)) + offx;
            float iy = (float)(h + (p % 3)) + offy;
            float x0f = floorf(ix), y0f = floorf(iy);
            float fx = ix - x0f, fy = iy - y0f;
            int x0 = (int)x0f, y0 = (int)y0f;
            int xi[4] = { x0, x0 + 1, x0,     x0 + 1 };
            int yi[4] = { y0, y0,     y0 + 1, y0 + 1 };
            float wt[4] = { m * (1.f - fx) * (1.f - fy), m * fx * (1.f - fy),
                            m * (1.f - fx) * fy,         m * fx * fy };
            int lo[4];
            #pragma unroll
            for (int cnr = 0; cnr < 4; cnr++) {
                bool vv = ((unsigned)xi[cnr] < (unsigned)WP) && ((unsigned)yi[cnr] < (unsigned)HP);
                int xc = min(max(xi[cnr], 0), WP - 1), yc = min(max(yi[cnr], 0), HP - 1);
                lo[cnr] = (yc * WP + xc) * CH;
                if (!vv) wt[cnr] = 0.f;
            }
            *(int4*)&tm[p * 8]       = make_int4(lo[0], lo[1], lo[2], lo[3]);
            *(float4*)&tm[p * 8 + 4] = make_float4(wt[0], wt[1], wt[2], wt[3]);
        }
    }
}

// ---- g5: fused gather sampling + out_proj MFMA + NHWC->NCHW store ----------
// thread t -> px = t>>3 (0..63), slot s = t&7 -> ch [s*16, s*16+16), group s>>1
__global__ __launch_bounds__(512) void g5_gather_outproj(const _Float16* __restrict__ xpad16,
                                                         const float* __restrict__ tapmeta,
                                                         const _Float16* __restrict__ wp,
                                                         const float* __restrict__ bias,
                                                         float* __restrict__ out) {
    __shared__ char smem[50432];                    // a16(17408) + res(33024)
    _Float16* a16 = (_Float16*)smem;
    float* res = (float*)(smem + 17408);
    int t = threadIdx.x;
    int pix0 = blockIdx.x * 64;
    int b = pix0 >> 12, h = (pix0 >> 6) & 63;
    int px = t >> 3, s = t & 7;
    int ch = s * 16, g = s >> 1;
    int pix = pix0 + px;
    const _Float16* base = xpad16 + (size_t)b * HP * WP * CH + ch;
    const float* tmbase = tapmeta + ((size_t)pix * 36 + g * 9) * 8;
    float acc[16];
    #pragma unroll
    for (int j = 0; j < 16; j++) acc[j] = 0.f;
    #pragma unroll
    for (int p = 0; p < 9; p++) {
        int4   o  = *(const int4*)&tmbase[p * 8];
        float4 wv = *(const float4*)&tmbase[p * 8 + 4];
        v8h c0a = *(const v8h*)&base[o.x];
        v8h c0b = *(const v8h*)&base[o.x + 8];
        v8h c1a = *(const v8h*)&base[o.y];
        v8h c1b = *(const v8h*)&base[o.y + 8];
        v8h c2a = *(const v8h*)&base[o.z];
        v8h c2b = *(const v8h*)&base[o.z + 8];
        v8h c3a = *(const v8h*)&base[o.w];
        v8h c3b = *(const v8h*)&base[o.w + 8];
        #pragma unroll
        for (int j = 0; j < 8; j++) {
            acc[j]     += wv.x*(float)c0a[j] + wv.y*(float)c1a[j] + wv.z*(float)c2a[j] + wv.w*(float)c3a[j];
            acc[j + 8] += wv.x*(float)c0b[j] + wv.y*(float)c1b[j] + wv.z*(float)c2b[j] + wv.w*(float)c3b[j];
        }
    }
    v8h r0, r1;
    #pragma unroll
    for (int j = 0; j < 8; j++) { r0[j] = (_Float16)acc[j]; r1[j] = (_Float16)acc[j + 8]; }
    *(v8h*)&a16[px * ASTRIDE + ch]     = r0;
    *(v8h*)&a16[px * ASTRIDE + ch + 8] = r1;
    __syncthreads();
    // out_proj MFMA (8-wave split)
    int lane = t & 63, ncol = lane & 15;
    int ntb = ((t >> 6) & 1) * 4;
    v4f macc[4];
    #pragma unroll
    for (int j = 0; j < 4; j++) {
        float bv = bias[(ntb + j) * 16 + ncol];
        macc[j] = (v4f){bv, bv, bv, bv};
    }
    mfma_loop8(a16, wp, macc, t);
    int m0 = ((t >> 6) >> 1) * 16 + ((lane >> 4) * 4);
    #pragma unroll
    for (int j = 0; j < 4; j++)
        #pragma unroll
        for (int r = 0; r < 4; r++)
            res[(m0 + r) * 129 + (ntb + j) * 16 + ncol] = macc[j][r];
    __syncthreads();
    // vectorized NCHW store: cc = q>>4, w4 = (q&15)*4
    for (int q = t; q < 2048; q += 512) {
        int cc = q >> 4, w4 = (q & 15) * 4;
        float4 o;
        o.x = res[(w4 + 0) * 129 + cc];
        o.y = res[(w4 + 1) * 129 + cc];
        o.z = res[(w4 + 2) * 129 + cc];
        o.w = res[(w4 + 3) * 129 + cc];
        *(float4*)&out[(size_t)((b * CH + cc) * HH + h) * WWID + w4] = o;
    }
}

extern "C" void kernel_launch(void* const* d_in, const int* in_sizes, int n_in,
                              void* d_out, int out_size, void* d_ws, size_t ws_size,
                              hipStream_t stream) {
    const float* x        = (const float*)d_in[0];
    const float* conv_w   = (const float*)d_in[1];
    const float* conv_b   = (const float*)d_in[2];
    const float* in_proj_w= (const float*)d_in[3];
    const float* in_proj_b= (const float*)d_in[4];
    const float* dw_w     = (const float*)d_in[5];
    const float* dw_b     = (const float*)d_in[6];
    const float* ln_g     = (const float*)d_in[7];
    const float* ln_b     = (const float*)d_in[8];
    const float* off_w    = (const float*)d_in[9];
    const float* off_b    = (const float*)d_in[10];
    const float* mask_w   = (const float*)d_in[11];
    const float* mask_b   = (const float*)d_in[12];
    const float* out_proj_w = (const float*)d_in[13];
    const float* out_proj_b = (const float*)d_in[14];
    float* out = (float*)d_out;

    float* ws = (float*)d_ws;
    // float-offsets: wp(32768) | dwT(2048) | y16 | xpad16 | tapmeta
    const size_t O_WP   = 0;
    const size_t O_DWT  = 32768;
    const size_t O_Y16  = 34816;                   // 2,097,152 floats (as halfs)
    const size_t O_XP16 = O_Y16 + 2097152;         // 2,230,272 floats
    const size_t O_TM   = O_XP16 + 2230272;        // 9,437,184 floats
    _Float16* wp     = (_Float16*)(ws + O_WP);
    float*    dwT    = ws + O_DWT;
    _Float16* y16    = (_Float16*)(ws + O_Y16);
    _Float16* xpad16 = (_Float16*)(ws + O_XP16);
    float*    tapmeta= ws + O_TM;

    _Float16* wp_conv = wp;
    _Float16* wp_in   = wp + (size_t)2048 * 8;
    _Float16* wp_om   = wp + (size_t)4096 * 8;
    _Float16* wp_out  = wp + (size_t)5888 * 8;

    p0_pack<<<32, 256, 0, stream>>>(conv_w, in_proj_w, off_w, mask_w, out_proj_w, dw_w, wp, dwT);
    hipMemsetAsync(xpad16, 0, (size_t)8 * HP * WP * CH * sizeof(_Float16), stream);
    gA_conv_inproj<<<NPIX / 64, 512, 0, stream>>>(x, wp_conv, wp_in, conv_b, in_proj_b, y16, xpad16);
    gF_dwln_offmask<<<NPIX / 64, 512, 0, stream>>>(y16, wp_om, dwT, dw_b, ln_g, ln_b, off_b, mask_b, tapmeta);
    g5_gather_outproj<<<NPIX / 64, 512, 0, stream>>>(xpad16, tapmeta, wp_out, out_proj_b, out);
}

// Round 10
// 165.637 us; speedup vs baseline: 1.4461x; 1.4461x over previous
//
#include <hip/hip_runtime.h>
#include <math.h>

#define BB 8
#define CH 128
#define HH 64
#define WWID 64
#define HIN 62
#define WIN 62
#define SPIN (HIN*WIN)      // 3844
#define HP 66
#define WP 66
#define GP2 70              // padded + 2-guard each side
#define GG 4
#define GCH 32
#define NPIX (BB*HH*WWID)   // 32768
#define ASTRIDE 136         // LDS A-tile row stride in halfs

typedef _Float16 v8h __attribute__((ext_vector_type(8)));
typedef _Float16 v4h __attribute__((ext_vector_type(4)));
typedef float    v4f __attribute__((ext_vector_type(4)));
typedef float    f4a __attribute__((ext_vector_type(4), aligned(4)));

// ---- P0: pack 4 weight mats into MFMA B-frag order (f16) + dwT transpose ---
__global__ __launch_bounds__(256) void p0_pack(const float* __restrict__ conv_w,
                                               const float* __restrict__ in_proj_w,
                                               const float* __restrict__ off_w,
                                               const float* __restrict__ mask_w,
                                               const float* __restrict__ out_proj_w,
                                               const float* __restrict__ dw_w,
                                               _Float16* __restrict__ wp,
                                               float* __restrict__ dwT) {
    int t = threadIdx.x;
    if (blockIdx.x == 31) {
        if (t < 128) {
            #pragma unroll
            for (int tap = 0; tap < 9; tap++) dwT[tap * 128 + t] = dw_w[t * 9 + tap];
        }
        return;
    }
    int tid = blockIdx.x * 256 + t;                 // 0..7935
    int mat, base;
    if (tid < 2048)      { mat = 0; base = 0; }
    else if (tid < 4096) { mat = 1; base = 2048; }
    else if (tid < 5888) { mat = 2; base = 4096; }
    else                 { mat = 3; base = 5888; }
    int fi = tid - base;
    int nt = fi >> 8, rem = fi & 255, kc = rem >> 6, lane = rem & 63;
    int n = nt * 16 + (lane & 15);
    int kbase = kc * 32 + ((lane >> 4) & 3) * 8;
    _Float16* dst = wp + (size_t)tid * 8;
    #pragma unroll
    for (int j = 0; j < 8; j++) {
        int k = kbase + j;
        float v;
        if (mat == 0)      v = conv_w[n * CH + k];
        else if (mat == 1) v = in_proj_w[k * CH + n];
        else if (mat == 2) v = (n < 72) ? off_w[k * 72 + n]
                               : (n < 108 ? mask_w[k * 36 + (n - 72)] : 0.f);
        else               v = out_proj_w[k * CH + n];
        dst[j] = (_Float16)v;
    }
}

// ---- MFMA core, 8-wave split ----------------------------------------------
__device__ inline void mfma_loop8(const _Float16* __restrict__ a16,
                                  const _Float16* __restrict__ wp,
                                  v4f acc[4], int t) {
    int lane = t & 63;
    int wv = t >> 6;
    int mt = wv >> 1, ntb = (wv & 1) * 4;
    const _Float16* abase = a16 + (mt * 16 + (lane & 15)) * ASTRIDE + ((lane >> 4) * 8);
    #pragma unroll
    for (int kc = 0; kc < 4; kc++) {
        v8h av = *(const v8h*)(abase + kc * 32);
        #pragma unroll
        for (int j = 0; j < 4; j++) {
            v8h bv = *(const v8h*)(wp + ((size_t)((ntb + j) * 4 + kc) * 64 + lane) * 8);
            acc[j] = __builtin_amdgcn_mfma_f32_16x16x32_f16(av, bv, acc[j], 0, 0, 0);
        }
    }
}

__device__ inline void acc_to_a16_8(_Float16* a16, v4f acc[4], int t) {
    int lane = t & 63, ncol = lane & 15;
    int wv = t >> 6;
    int m0 = (wv >> 1) * 16 + ((lane >> 4) * 4);
    int ntb = (wv & 1) * 4;
    #pragma unroll
    for (int j = 0; j < 4; j++)
        #pragma unroll
        for (int r = 0; r < 4; r++)
            a16[(m0 + r) * ASTRIDE + (ntb + j) * 16 + ncol] = (_Float16)acc[j][r];
}

// ---- gA: fused conv1x1(pad=1) + in_proj; emits y16 + xpad16 (70x70 guard) --
__global__ __launch_bounds__(512) void gA_conv_inproj(const float* __restrict__ x,
                                                      const _Float16* __restrict__ wp_conv,
                                                      const _Float16* __restrict__ wp_in,
                                                      const float* __restrict__ conv_b,
                                                      const float* __restrict__ in_b,
                                                      _Float16* __restrict__ y16,
                                                      _Float16* __restrict__ xpad16) {
    __shared__ _Float16 a16[64 * ASTRIDE];
    int pix0 = blockIdx.x * 64;                     // one row
    int t = threadIdx.x;
    int h = (pix0 >> 6) & 63, b = pix0 >> 12;
    bool hin = (h >= 1 && h <= 62);
    for (int q = t; q < 2048; q += 512) {
        int c = q >> 4, w4 = (q & 15) * 4;
        float4 v = make_float4(0.f, 0.f, 0.f, 0.f);
        if (hin) {
            const float* xr = x + ((size_t)(b * CH + c)) * SPIN + (h - 1) * WIN;
            if (w4 == 0)       { f4a e = *(const f4a*)&xr[0];      v = make_float4(0.f, e[0], e[1], e[2]); }
            else if (w4 == 60) { f4a e = *(const f4a*)&xr[58];     v = make_float4(e[1], e[2], e[3], 0.f); }
            else               { f4a e = *(const f4a*)&xr[w4 - 1]; v = make_float4(e[0], e[1], e[2], e[3]); }
        }
        a16[(w4 + 0) * ASTRIDE + c] = (_Float16)v.x;
        a16[(w4 + 1) * ASTRIDE + c] = (_Float16)v.y;
        a16[(w4 + 2) * ASTRIDE + c] = (_Float16)v.z;
        a16[(w4 + 3) * ASTRIDE + c] = (_Float16)v.w;
    }
    __syncthreads();
    int lane = t & 63, ncol = lane & 15;
    int ntb = ((t >> 6) & 1) * 4;
    v4f acc[4];
    #pragma unroll
    for (int j = 0; j < 4; j++) {
        float bv = conv_b[(ntb + j) * 16 + ncol];
        acc[j] = (v4f){bv, bv, bv, bv};
    }
    mfma_loop8(a16, wp_conv, acc, t);
    __syncthreads();
    acc_to_a16_8(a16, acc, t);                      // a16 = y tile
    __syncthreads();
    {
        _Float16* dst = y16 + (size_t)pix0 * CH;
        for (int q = t; q < 1024; q += 512)
            *(v8h*)&dst[q * 8] = *(const v8h*)&a16[(q >> 4) * ASTRIDE + (q & 15) * 8];
    }
    v4f acc2[4];
    #pragma unroll
    for (int j = 0; j < 4; j++) {
        float bv = in_b[(ntb + j) * 16 + ncol];
        acc2[j] = (v4f){bv, bv, bv, bv};
    }
    mfma_loop8(a16, wp_in, acc2, t);
    __syncthreads();
    acc_to_a16_8(a16, acc2, t);                     // a16 = x_proj tile
    __syncthreads();
    {
        // interior pixel (h,w) -> padded (h+1, w+1) -> +2 guard = (h+3, w+3)
        _Float16* dst = xpad16 + (size_t)(((b * GP2) + h + 3) * GP2 + 3) * CH;
        for (int q = t; q < 1024; q += 512)
            *(v8h*)&dst[q * 8] = *(const v8h*)&a16[(q >> 4) * ASTRIDE + (q & 15) * 8];
    }
}

// ---- gF: fused dw3x3 + LN + GELU + off/mask MFMA + softmax + taps ----------
// tap record (16 B): [int base_off | f32 fx | f32 fy | f32 m]
__global__ __launch_bounds__(512) void gF_dwln_offmask(const _Float16* __restrict__ y16,
                                                       const _Float16* __restrict__ wp_om,
                                                       const float* __restrict__ dwT,
                                                       const float* __restrict__ dw_b,
                                                       const float* __restrict__ ln_g,
                                                       const float* __restrict__ ln_b,
                                                       const float* __restrict__ off_b,
                                                       const float* __restrict__ mask_b,
                                                       float* __restrict__ tapmeta) {
    __shared__ char smem[49920];
    _Float16* ylds = (_Float16*)smem;               // v8h idx: (r*16+c8)*65 + w
    int t = threadIdx.x;
    int pix0 = blockIdx.x * 64;
    int h = (pix0 >> 6) & 63, b = pix0 >> 12;
    if (h == 0 || h == 63) {
        for (int i = t; i < 3120; i += 512) *(v8h*)&ylds[i * 8] = (v8h)(_Float16)0;
        __syncthreads();
    }
    for (int idx = t; idx < 3072; idx += 512) {
        int r = idx >> 10, w = (idx >> 4) & 63, c8 = idx & 15;
        int hh = h + r - 1;
        if (hh >= 0 && hh <= 63) {
            v8h v = *(const v8h*)&y16[(size_t)(((b * 64 + hh) * 64 + w) * CH) + c8 * 8];
            *(v8h*)&ylds[(size_t)((r * 16 + c8) * 65 + w) * 8] = v;
        }
    }
    __syncthreads();
    int px = t >> 3, q8 = t & 7;
    float acc[16];
    #pragma unroll
    for (int cb = 0; cb < 4; cb++) *(float4*)&acc[cb * 4] = *(const float4*)&dw_b[q8 * 16 + cb * 4];
    #pragma unroll
    for (int r = 0; r < 3; r++) {
        #pragma unroll
        for (int kx = 0; kx < 3; kx++) {
            int wq = px + kx - 1;
            bool valid = (wq >= 0 && wq <= 63);
            int wpc = min(max(wq, 0), 63);
            int tap = r * 3 + kx;
            if (valid) {
                #pragma unroll
                for (int cb = 0; cb < 2; cb++) {
                    v8h yv = *(const v8h*)&ylds[(size_t)((r * 16 + q8 * 2 + cb) * 65 + wpc) * 8];
                    float4 wa = *(const float4*)&dwT[tap * 128 + q8 * 16 + cb * 8];
                    float4 wb = *(const float4*)&dwT[tap * 128 + q8 * 16 + cb * 8 + 4];
                    acc[cb*8+0] += (float)yv[0] * wa.x; acc[cb*8+1] += (float)yv[1] * wa.y;
                    acc[cb*8+2] += (float)yv[2] * wa.z; acc[cb*8+3] += (float)yv[3] * wa.w;
                    acc[cb*8+4] += (float)yv[4] * wb.x; acc[cb*8+5] += (float)yv[5] * wb.y;
                    acc[cb*8+6] += (float)yv[6] * wb.z; acc[cb*8+7] += (float)yv[7] * wb.w;
                }
            }
        }
    }
    float s = 0.f, ss = 0.f;
    #pragma unroll
    for (int j = 0; j < 16; j++) { s += acc[j]; ss += acc[j] * acc[j]; }
    s  += __shfl_xor(s, 1);  s  += __shfl_xor(s, 2);  s  += __shfl_xor(s, 4);
    ss += __shfl_xor(ss, 1); ss += __shfl_xor(ss, 2); ss += __shfl_xor(ss, 4);
    float mu = s * (1.f / 128.f);
    float var = ss * (1.f / 128.f) - mu * mu;
    float rstd = rsqrtf(var + 1e-5f);
    v8h dreg[2];
    #pragma unroll
    for (int cb = 0; cb < 2; cb++) {
        float4 ga = *(const float4*)&ln_g[q8 * 16 + cb * 8];
        float4 gb = *(const float4*)&ln_g[q8 * 16 + cb * 8 + 4];
        float4 ba = *(const float4*)&ln_b[q8 * 16 + cb * 8];
        float4 bb = *(const float4*)&ln_b[q8 * 16 + cb * 8 + 4];
        float gv[8] = {ga.x, ga.y, ga.z, ga.w, gb.x, gb.y, gb.z, gb.w};
        float bv[8] = {ba.x, ba.y, ba.z, ba.w, bb.x, bb.y, bb.z, bb.w};
        #pragma unroll
        for (int j = 0; j < 8; j++) {
            float xln = (acc[cb * 8 + j] - mu) * rstd * gv[j] + bv[j];
            float gel = 0.5f * xln * (1.f + erff(xln * 0.70710678118654752f));
            dreg[cb][j] = (_Float16)gel;
        }
    }
    __syncthreads();
    _Float16* a16 = (_Float16*)smem;
    float* om = (float*)(smem + 17408);
    #pragma unroll
    for (int cb = 0; cb < 2; cb++)
        *(v8h*)&a16[px * ASTRIDE + q8 * 16 + cb * 8] = dreg[cb];
    __syncthreads();
    int lane = t & 63, ncol = lane & 15;
    int ntb = ((t >> 6) & 1) * 4;
    v4f macc[4];
    #pragma unroll
    for (int j = 0; j < 4; j++) {
        int n = (ntb + j) * 16 + ncol;
        float bv = (n < 72) ? off_b[n] : (n < 108 ? mask_b[n - 72] : 0.f);
        macc[j] = (v4f){bv, bv, bv, bv};
    }
    mfma_loop8(a16, wp_om, macc, t);
    int m0 = ((t >> 6) >> 1) * 16 + ((lane >> 4) * 4);
    #pragma unroll
    for (int j = 0; j < 4; j++) {
        if (ntb + j < 7) {
            #pragma unroll
            for (int r = 0; r < 4; r++)
                om[(m0 + r) * 112 + (ntb + j) * 16 + ncol] = macc[j][r];
        }
    }
    __syncthreads();
    if (t < 256) {
        int pxs = t >> 2, gx = t & 3;
        const float* row = &om[pxs * 112];
        float lg[9];
        #pragma unroll
        for (int i = 0; i < 9; i++) lg[i] = row[72 + gx * 9 + i];
        float mx = lg[0];
        #pragma unroll
        for (int i = 1; i < 9; i++) mx = fmaxf(mx, lg[i]);
        float e[9], sum = 0.f;
        #pragma unroll
        for (int i = 0; i < 9; i++) { e[i] = expf(lg[i] - mx); sum += e[i]; }
        float inv = 1.f / sum;
        float* tm = tapmeta + ((size_t)(pix0 + pxs) * 36 + gx * 9) * 4;
        #pragma unroll
        for (int p = 0; p < 9; p++) {
            int gp = gx * 9 + p;
            float offx = row[gp * 2];
            float offy = row[gp * 2 + 1];
            float m = e[p] * inv;
            float ix = (float)(pxs + (p / 3)) + offx;
            float iy = (float)(h + (p % 3)) + offy;
            // clamp into guard range: all-OOB results stay all-OOB (-> 0)
            ix = fminf(fmaxf(ix, -2.f), (float)(WP + 1));
            iy = fminf(fmaxf(iy, -2.f), (float)(HP + 1));
            float x0f = floorf(ix), y0f = floorf(iy);
            float fx = ix - x0f, fy = iy - y0f;
            int x0 = (int)x0f, y0 = (int)y0f;          // in [-2, DIM+1]
            int off = ((y0 + 2) * GP2 + (x0 + 2)) * CH; // guard-shifted base corner
            float4 rec;
            rec.x = __int_as_float(off);
            rec.y = fx; rec.z = fy; rec.w = m;
            *(float4*)&tm[p * 4] = rec;
        }
    }
}

// ---- kD: gather sampling, 8 px/block, 4 ch/thread -> core16 ----------------
__global__ __launch_bounds__(256) void kD_gather(const _Float16* __restrict__ xpad16,
                                                 const float* __restrict__ tapmeta,
                                                 _Float16* __restrict__ core16) {
    __shared__ float meta[8 * 36 * 4];              // 4608 B = 288 float4
    int t = threadIdx.x;
    int pix0 = blockIdx.x * 8;
    const float4* src = (const float4*)(tapmeta + (size_t)pix0 * 36 * 4);
    for (int i = t; i < 288; i += 256) ((float4*)meta)[i] = src[i];   // FIX: loop, 288 > blockDim
    __syncthreads();
    int px_l = t >> 5, lane5 = t & 31;
    int c4 = lane5 * 4, g = lane5 >> 3;
    int pix = pix0 + px_l;
    int b = pix >> 12;
    const _Float16* base = xpad16 + (size_t)b * GP2 * GP2 * CH + c4;
    float a0 = 0.f, a1 = 0.f, a2 = 0.f, a3 = 0.f;
    #pragma unroll
    for (int p = 0; p < 9; p++) {
        float4 rec = *(const float4*)&meta[(size_t)(px_l * 36 + g * 9 + p) * 4];
        int off = __float_as_int(rec.x);
        float fx = rec.y, fy = rec.z, m = rec.w;
        float w11 = fx * fy;
        float w10 = fx - w11;          // fx*(1-fy)
        float w01 = fy - w11;          // (1-fx)*fy
        float w00 = 1.f - fx - fy + w11;
        w00 *= m; w10 *= m; w01 *= m; w11 *= m;
        v4h h0 = *(const v4h*)&base[off];
        v4h h1 = *(const v4h*)&base[off + CH];
        v4h h2 = *(const v4h*)&base[off + GP2 * CH];
        v4h h3 = *(const v4h*)&base[off + GP2 * CH + CH];
        a0 += w00*(float)h0[0] + w10*(float)h1[0] + w01*(float)h2[0] + w11*(float)h3[0];
        a1 += w00*(float)h0[1] + w10*(float)h1[1] + w01*(float)h2[1] + w11*(float)h3[1];
        a2 += w00*(float)h0[2] + w10*(float)h1[2] + w01*(float)h2[2] + w11*(float)h3[2];
        a3 += w00*(float)h0[3] + w10*(float)h1[3] + w01*(float)h2[3] + w11*(float)h3[3];
    }
    v4h res = { (_Float16)a0, (_Float16)a1, (_Float16)a2, (_Float16)a3 };
    *(v4h*)&core16[(size_t)pix * CH + c4] = res;
}

// ---- g4: out_proj via MFMA + NHWC->NCHW store ------------------------------
__global__ __launch_bounds__(512) void g4_outproj(const _Float16* __restrict__ core16,
                                                  const _Float16* __restrict__ wp,
                                                  const float* __restrict__ bias,
                                                  float* __restrict__ out) {
    __shared__ _Float16 a16[64 * ASTRIDE];
    __shared__ float res[64 * 129];
    int pix0 = blockIdx.x * 64;
    int t = threadIdx.x;
    const _Float16* src = core16 + (size_t)pix0 * CH;
    for (int q = t; q < 1024; q += 512)
        *(v8h*)&a16[(q >> 4) * ASTRIDE + (q & 15) * 8] = *(const v8h*)&src[q * 8];
    __syncthreads();
    int lane = t & 63, ncol = lane & 15;
    int ntb = ((t >> 6) & 1) * 4;
    v4f acc[4];
    #pragma unroll
    for (int j = 0; j < 4; j++) {
        float bv = bias[(ntb + j) * 16 + ncol];
        acc[j] = (v4f){bv, bv, bv, bv};
    }
    mfma_loop8(a16, wp, acc, t);
    int m0 = ((t >> 6) >> 1) * 16 + ((lane >> 4) * 4);
    #pragma unroll
    for (int j = 0; j < 4; j++)
        #pragma unroll
        for (int r = 0; r < 4; r++)
            res[(m0 + r) * 129 + (ntb + j) * 16 + ncol] = acc[j][r];
    __syncthreads();
    int b = pix0 >> 12, h = (pix0 >> 6) & 63;
    for (int q = t; q < 2048; q += 512) {
        int cc = q >> 4, w4 = (q & 15) * 4;
        float4 o;
        o.x = res[(w4 + 0) * 129 + cc];
        o.y = res[(w4 + 1) * 129 + cc];
        o.z = res[(w4 + 2) * 129 + cc];
        o.w = res[(w4 + 3) * 129 + cc];
        *(float4*)&out[(size_t)((b * CH + cc) * HH + h) * WWID + w4] = o;
    }
}

extern "C" void kernel_launch(void* const* d_in, const int* in_sizes, int n_in,
                              void* d_out, int out_size, void* d_ws, size_t ws_size,
                              hipStream_t stream) {
    const float* x        = (const float*)d_in[0];
    const float* conv_w   = (const float*)d_in[1];
    const float* conv_b   = (const float*)d_in[2];
    const float* in_proj_w= (const float*)d_in[3];
    const float* in_proj_b= (const float*)d_in[4];
    const float* dw_w     = (const float*)d_in[5];
    const float* dw_b     = (const float*)d_in[6];
    const float* ln_g     = (const float*)d_in[7];
    const float* ln_b     = (const float*)d_in[8];
    const float* off_w    = (const float*)d_in[9];
    const float* off_b    = (const float*)d_in[10];
    const float* mask_w   = (const float*)d_in[11];
    const float* mask_b   = (const float*)d_in[12];
    const float* out_proj_w = (const float*)d_in[13];
    const float* out_proj_b = (const float*)d_in[14];
    float* out = (float*)d_out;

    float* ws = (float*)d_ws;
    // float-offsets: wp | dwT | y16 | xpad16(70x70 guard) | core16 | tapmeta
    const size_t O_WP   = 0;                        // 124 KB (reserve 32768 floats)
    const size_t O_DWT  = 32768;
    const size_t O_Y16  = 34816;                    // 2,097,152 floats (halfs)
    const size_t O_XP16 = O_Y16 + 2097152;          // 8*70*70*128 halfs = 2,508,800 floats
    const size_t O_C16  = O_XP16 + 2508800;         // 2,097,152 floats
    const size_t O_TM   = O_C16 + 2097152;          // 32768*36*4 = 4,718,592 floats
    _Float16* wp     = (_Float16*)(ws + O_WP);
    float*    dwT    = ws + O_DWT;
    _Float16* y16    = (_Float16*)(ws + O_Y16);
    _Float16* xpad16 = (_Float16*)(ws + O_XP16);
    _Float16* core16 = (_Float16*)(ws + O_C16);
    float*    tapmeta= ws + O_TM;

    _Float16* wp_conv = wp;
    _Float16* wp_in   = wp + (size_t)2048 * 8;
    _Float16* wp_om   = wp + (size_t)4096 * 8;
    _Float16* wp_out  = wp + (size_t)5888 * 8;

    p0_pack<<<32, 256, 0, stream>>>(conv_w, in_proj_w, off_w, mask_w, out_proj_w, dw_w, wp, dwT);
    hipMemsetAsync(xpad16, 0, (size_t)8 * GP2 * GP2 * CH * sizeof(_Float16), stream);
    gA_conv_inproj<<<NPIX / 64, 512, 0, stream>>>(x, wp_conv, wp_in, conv_b, in_proj_b, y16, xpad16);
    gF_dwln_offmask<<<NPIX / 64, 512, 0, stream>>>(y16, wp_om, dwT, dw_b, ln_g, ln_b, off_b, mask_b, tapmeta);
    kD_gather<<<NPIX / 8, 256, 0, stream>>>(xpad16, tapmeta, core16);
    g4_outproj<<<NPIX / 64, 512, 0, stream>>>(core16, wp_out, out_proj_b, out);
}

// Round 11
// 162.680 us; speedup vs baseline: 1.4724x; 1.0182x over previous
//
#include <hip/hip_runtime.h>
#include <math.h>

#define BB 8
#define CH 128
#define HH 64
#define WWID 64
#define HIN 62
#define WIN 62
#define SPIN (HIN*WIN)      // 3844
#define HP 66
#define WP 66
#define GP2 70              // padded + 2-guard each side
#define GG 4
#define GCH 32
#define NPIX (BB*HH*WWID)   // 32768
#define ASTRIDE 136         // LDS A-tile row stride in halfs
#define XPHALFS ((size_t)BB*GP2*GP2*CH)   // 5,017,600 halfs

typedef _Float16 v8h __attribute__((ext_vector_type(8)));
typedef _Float16 v4h __attribute__((ext_vector_type(4)));
typedef float    v4f __attribute__((ext_vector_type(4)));
typedef float    f4a __attribute__((ext_vector_type(4), aligned(4)));

// ---- P0: pack weights into MFMA B-frag order + dwT + zero xpad -------------
__global__ __launch_bounds__(256) void p0_pack(const float* __restrict__ conv_w,
                                               const float* __restrict__ in_proj_w,
                                               const float* __restrict__ off_w,
                                               const float* __restrict__ mask_w,
                                               const float* __restrict__ out_proj_w,
                                               const float* __restrict__ dw_w,
                                               _Float16* __restrict__ wp,
                                               float* __restrict__ dwT,
                                               _Float16* __restrict__ xpad16) {
    int t = threadIdx.x;
    int blk = blockIdx.x;
    if (blk >= 32) {                                 // blocks 32..63: zero xpad
        size_t nvec = XPHALFS / 8;                   // 627,200 v8h units
        for (size_t i = (size_t)(blk - 32) * 256 + t; i < nvec; i += 32 * 256)
            *(v8h*)&xpad16[i * 8] = (v8h)(_Float16)0;
        return;
    }
    if (blk == 31) {                                 // dwT[tap][c] transpose
        if (t < 128) {
            #pragma unroll
            for (int tap = 0; tap < 9; tap++) dwT[tap * 128 + t] = dw_w[t * 9 + tap];
        }
        return;
    }
    int tid = blk * 256 + t;                         // 0..7935
    int mat, base;
    if (tid < 2048)      { mat = 0; base = 0; }
    else if (tid < 4096) { mat = 1; base = 2048; }
    else if (tid < 5888) { mat = 2; base = 4096; }
    else                 { mat = 3; base = 5888; }
    int fi = tid - base;
    int nt = fi >> 8, rem = fi & 255, kc = rem >> 6, lane = rem & 63;
    int n = nt * 16 + (lane & 15);
    int kbase = kc * 32 + ((lane >> 4) & 3) * 8;
    _Float16* dst = wp + (size_t)tid * 8;
    #pragma unroll
    for (int j = 0; j < 8; j++) {
        int k = kbase + j;
        float v;
        if (mat == 0)      v = conv_w[n * CH + k];
        else if (mat == 1) v = in_proj_w[k * CH + n];
        else if (mat == 2) v = (n < 72) ? off_w[k * 72 + n]
                               : (n < 108 ? mask_w[k * 36 + (n - 72)] : 0.f);
        else               v = out_proj_w[k * CH + n];
        dst[j] = (_Float16)v;
    }
}

// ---- MFMA core, 8-wave split ----------------------------------------------
__device__ inline void mfma_loop8(const _Float16* __restrict__ a16,
                                  const _Float16* __restrict__ wp,
                                  v4f acc[4], int t) {
    int lane = t & 63;
    int wv = t >> 6;
    int mt = wv >> 1, ntb = (wv & 1) * 4;
    const _Float16* abase = a16 + (mt * 16 + (lane & 15)) * ASTRIDE + ((lane >> 4) * 8);
    #pragma unroll
    for (int kc = 0; kc < 4; kc++) {
        v8h av = *(const v8h*)(abase + kc * 32);
        #pragma unroll
        for (int j = 0; j < 4; j++) {
            v8h bv = *(const v8h*)(wp + ((size_t)((ntb + j) * 4 + kc) * 64 + lane) * 8);
            acc[j] = __builtin_amdgcn_mfma_f32_16x16x32_f16(av, bv, acc[j], 0, 0, 0);
        }
    }
}

__device__ inline void acc_to_a16_8(_Float16* a16, v4f acc[4], int t) {
    int lane = t & 63, ncol = lane & 15;
    int wv = t >> 6;
    int m0 = (wv >> 1) * 16 + ((lane >> 4) * 4);
    int ntb = (wv & 1) * 4;
    #pragma unroll
    for (int j = 0; j < 4; j++)
        #pragma unroll
        for (int r = 0; r < 4; r++)
            a16[(m0 + r) * ASTRIDE + (ntb + j) * 16 + ncol] = (_Float16)acc[j][r];
}

// ---- gA: fused conv1x1(pad=1) + in_proj; emits y16 + xpad16 (70x70 guard) --
__global__ __launch_bounds__(512) void gA_conv_inproj(const float* __restrict__ x,
                                                      const _Float16* __restrict__ wp_conv,
                                                      const _Float16* __restrict__ wp_in,
                                                      const float* __restrict__ conv_b,
                                                      const float* __restrict__ in_b,
                                                      _Float16* __restrict__ y16,
                                                      _Float16* __restrict__ xpad16) {
    __shared__ _Float16 a16[64 * ASTRIDE];
    int pix0 = blockIdx.x * 64;                     // one row
    int t = threadIdx.x;
    int h = (pix0 >> 6) & 63, b = pix0 >> 12;
    bool hin = (h >= 1 && h <= 62);
    for (int q = t; q < 2048; q += 512) {
        int c = q >> 4, w4 = (q & 15) * 4;
        float4 v = make_float4(0.f, 0.f, 0.f, 0.f);
        if (hin) {
            const float* xr = x + ((size_t)(b * CH + c)) * SPIN + (h - 1) * WIN;
            if (w4 == 0)       { f4a e = *(const f4a*)&xr[0];      v = make_float4(0.f, e[0], e[1], e[2]); }
            else if (w4 == 60) { f4a e = *(const f4a*)&xr[58];     v = make_float4(e[1], e[2], e[3], 0.f); }
            else               { f4a e = *(const f4a*)&xr[w4 - 1]; v = make_float4(e[0], e[1], e[2], e[3]); }
        }
        a16[(w4 + 0) * ASTRIDE + c] = (_Float16)v.x;
        a16[(w4 + 1) * ASTRIDE + c] = (_Float16)v.y;
        a16[(w4 + 2) * ASTRIDE + c] = (_Float16)v.z;
        a16[(w4 + 3) * ASTRIDE + c] = (_Float16)v.w;
    }
    __syncthreads();
    int lane = t & 63, ncol = lane & 15;
    int ntb = ((t >> 6) & 1) * 4;
    v4f acc[4];
    #pragma unroll
    for (int j = 0; j < 4; j++) {
        float bv = conv_b[(ntb + j) * 16 + ncol];
        acc[j] = (v4f){bv, bv, bv, bv};
    }
    mfma_loop8(a16, wp_conv, acc, t);
    __syncthreads();
    acc_to_a16_8(a16, acc, t);                      // a16 = y tile
    __syncthreads();
    {
        _Float16* dst = y16 + (size_t)pix0 * CH;
        for (int q = t; q < 1024; q += 512)
            *(v8h*)&dst[q * 8] = *(const v8h*)&a16[(q >> 4) * ASTRIDE + (q & 15) * 8];
    }
    v4f acc2[4];
    #pragma unroll
    for (int j = 0; j < 4; j++) {
        float bv = in_b[(ntb + j) * 16 + ncol];
        acc2[j] = (v4f){bv, bv, bv, bv};
    }
    mfma_loop8(a16, wp_in, acc2, t);
    __syncthreads();
    acc_to_a16_8(a16, acc2, t);                     // a16 = x_proj tile
    __syncthreads();
    {
        // interior pixel (h,w) -> padded (h+1, w+1) -> +2 guard = (h+3, w+3)
        _Float16* dst = xpad16 + (size_t)(((b * GP2) + h + 3) * GP2 + 3) * CH;
        for (int q = t; q < 1024; q += 512)
            *(v8h*)&dst[q * 8] = *(const v8h*)&a16[(q >> 4) * ASTRIDE + (q & 15) * 8];
    }
}

// ---- gF: fused dw3x3 + LN + GELU + off/mask MFMA + softmax + taps ----------
// tap record (16 B): [int base_off | f32 fx | f32 fy | f32 m]
__global__ __launch_bounds__(512) void gF_dwln_offmask(const _Float16* __restrict__ y16,
                                                       const _Float16* __restrict__ wp_om,
                                                       const float* __restrict__ dwT,
                                                       const float* __restrict__ dw_b,
                                                       const float* __restrict__ ln_g,
                                                       const float* __restrict__ ln_b,
                                                       const float* __restrict__ off_b,
                                                       const float* __restrict__ mask_b,
                                                       float* __restrict__ tapmeta) {
    __shared__ char smem[49920];
    _Float16* ylds = (_Float16*)smem;               // v8h idx: (r*16+c8)*65 + w
    int t = threadIdx.x;
    int pix0 = blockIdx.x * 64;
    int h = (pix0 >> 6) & 63, b = pix0 >> 12;
    if (h == 0 || h == 63) {
        for (int i = t; i < 3120; i += 512) *(v8h*)&ylds[i * 8] = (v8h)(_Float16)0;
        __syncthreads();
    }
    for (int idx = t; idx < 3072; idx += 512) {
        int r = idx >> 10, w = (idx >> 4) & 63, c8 = idx & 15;
        int hh = h + r - 1;
        if (hh >= 0 && hh <= 63) {
            v8h v = *(const v8h*)&y16[(size_t)(((b * 64 + hh) * 64 + w) * CH) + c8 * 8];
            *(v8h*)&ylds[(size_t)((r * 16 + c8) * 65 + w) * 8] = v;
        }
    }
    __syncthreads();
    int px = t >> 3, q8 = t & 7;
    float acc[16];
    #pragma unroll
    for (int cb = 0; cb < 4; cb++) *(float4*)&acc[cb * 4] = *(const float4*)&dw_b[q8 * 16 + cb * 4];
    #pragma unroll
    for (int r = 0; r < 3; r++) {
        #pragma unroll
        for (int kx = 0; kx < 3; kx++) {
            int wq = px + kx - 1;
            bool valid = (wq >= 0 && wq <= 63);
            int wpc = min(max(wq, 0), 63);
            int tap = r * 3 + kx;
            if (valid) {
                #pragma unroll
                for (int cb = 0; cb < 2; cb++) {
                    v8h yv = *(const v8h*)&ylds[(size_t)((r * 16 + q8 * 2 + cb) * 65 + wpc) * 8];
                    float4 wa = *(const float4*)&dwT[tap * 128 + q8 * 16 + cb * 8];
                    float4 wb = *(const float4*)&dwT[tap * 128 + q8 * 16 + cb * 8 + 4];
                    acc[cb*8+0] += (float)yv[0] * wa.x; acc[cb*8+1] += (float)yv[1] * wa.y;
                    acc[cb*8+2] += (float)yv[2] * wa.z; acc[cb*8+3] += (float)yv[3] * wa.w;
                    acc[cb*8+4] += (float)yv[4] * wb.x; acc[cb*8+5] += (float)yv[5] * wb.y;
                    acc[cb*8+6] += (float)yv[6] * wb.z; acc[cb*8+7] += (float)yv[7] * wb.w;
                }
            }
        }
    }
    float s = 0.f, ss = 0.f;
    #pragma unroll
    for (int j = 0; j < 16; j++) { s += acc[j]; ss += acc[j] * acc[j]; }
    s  += __shfl_xor(s, 1);  s  += __shfl_xor(s, 2);  s  += __shfl_xor(s, 4);
    ss += __shfl_xor(ss, 1); ss += __shfl_xor(ss, 2); ss += __shfl_xor(ss, 4);
    float mu = s * (1.f / 128.f);
    float var = ss * (1.f / 128.f) - mu * mu;
    float rstd = rsqrtf(var + 1e-5f);
    v8h dreg[2];
    #pragma unroll
    for (int cb = 0; cb < 2; cb++) {
        float4 ga = *(const float4*)&ln_g[q8 * 16 + cb * 8];
        float4 gb = *(const float4*)&ln_g[q8 * 16 + cb * 8 + 4];
        float4 ba = *(const float4*)&ln_b[q8 * 16 + cb * 8];
        float4 bb = *(const float4*)&ln_b[q8 * 16 + cb * 8 + 4];
        float gv[8] = {ga.x, ga.y, ga.z, ga.w, gb.x, gb.y, gb.z, gb.w};
        float bv[8] = {ba.x, ba.y, ba.z, ba.w, bb.x, bb.y, bb.z, bb.w};
        #pragma unroll
        for (int j = 0; j < 8; j++) {
            float xln = (acc[cb * 8 + j] - mu) * rstd * gv[j] + bv[j];
            float gel = 0.5f * xln * (1.f + erff(xln * 0.70710678118654752f));
            dreg[cb][j] = (_Float16)gel;
        }
    }
    __syncthreads();
    _Float16* a16 = (_Float16*)smem;
    float* om = (float*)(smem + 17408);
    #pragma unroll
    for (int cb = 0; cb < 2; cb++)
        *(v8h*)&a16[px * ASTRIDE + q8 * 16 + cb * 8] = dreg[cb];
    __syncthreads();
    int lane = t & 63, ncol = lane & 15;
    int ntb = ((t >> 6) & 1) * 4;
    v4f macc[4];
    #pragma unroll
    for (int j = 0; j < 4; j++) {
        int n = (ntb + j) * 16 + ncol;
        float bv = (n < 72) ? off_b[n] : (n < 108 ? mask_b[n - 72] : 0.f);
        macc[j] = (v4f){bv, bv, bv, bv};
    }
    mfma_loop8(a16, wp_om, macc, t);
    int m0 = ((t >> 6) >> 1) * 16 + ((lane >> 4) * 4);
    #pragma unroll
    for (int j = 0; j < 4; j++) {
        if (ntb + j < 7) {
            #pragma unroll
            for (int r = 0; r < 4; r++)
                om[(m0 + r) * 112 + (ntb + j) * 16 + ncol] = macc[j][r];
        }
    }
    __syncthreads();
    // ---- softmax + tap precompute: ALL 512 threads; 2 threads per (px,g) ---
    {
        int job = t >> 1, half = t & 1;             // job 0..255
        int pxs = job >> 2, gx = job & 3;
        const float* row = &om[pxs * 112];
        float lg[9];
        #pragma unroll
        for (int i = 0; i < 9; i++) lg[i] = row[72 + gx * 9 + i];
        float mx = lg[0];
        #pragma unroll
        for (int i = 1; i < 9; i++) mx = fmaxf(mx, lg[i]);
        float e[9], sum = 0.f;
        #pragma unroll
        for (int i = 0; i < 9; i++) { e[i] = expf(lg[i] - mx); sum += e[i]; }
        float inv = 1.f / sum;
        float* tm = tapmeta + ((size_t)(pix0 + pxs) * 36 + gx * 9) * 4;
        int pstart = half * 5;                      // 0..4 or 5..8
        int pcount = half ? 4 : 5;
        #pragma unroll
        for (int pp = 0; pp < 5; pp++) {
            if (pp >= pcount) break;
            int p = pstart + pp;
            int gp = gx * 9 + p;
            float offx = row[gp * 2];
            float offy = row[gp * 2 + 1];
            float m = e[p] * inv;
            float ix = (float)(pxs + (p / 3)) + offx;
            float iy = (float)(h + (p % 3)) + offy;
            ix = fminf(fmaxf(ix, -2.f), (float)(WP + 1));
            iy = fminf(fmaxf(iy, -2.f), (float)(HP + 1));
            float x0f = floorf(ix), y0f = floorf(iy);
            float fx = ix - x0f, fy = iy - y0f;
            int x0 = (int)x0f, y0 = (int)y0f;          // in [-2, DIM+1]
            int off = ((y0 + 2) * GP2 + (x0 + 2)) * CH;
            float4 rec;
            rec.x = __int_as_float(off);
            rec.y = fx; rec.z = fy; rec.w = m;
            *(float4*)&tm[p * 4] = rec;
        }
    }
}

// ---- kD: gather sampling, 8 px/block, 4 ch/thread -> core16 ----------------
__global__ __launch_bounds__(256) void kD_gather(const _Float16* __restrict__ xpad16,
                                                 const float* __restrict__ tapmeta,
                                                 _Float16* __restrict__ core16) {
    __shared__ float meta[8 * 36 * 4];              // 288 float4
    int t = threadIdx.x;
    int pix0 = blockIdx.x * 8;
    const float4* src = (const float4*)(tapmeta + (size_t)pix0 * 36 * 4);
    for (int i = t; i < 288; i += 256) ((float4*)meta)[i] = src[i];
    __syncthreads();
    int px_l = t >> 5, lane5 = t & 31;
    int c4 = lane5 * 4, g = lane5 >> 3;
    int pix = pix0 + px_l;
    int b = pix >> 12;
    const _Float16* base = xpad16 + (size_t)b * GP2 * GP2 * CH + c4;
    float a0 = 0.f, a1 = 0.f, a2 = 0.f, a3 = 0.f;
    #pragma unroll
    for (int p = 0; p < 9; p++) {
        float4 rec = *(const float4*)&meta[(size_t)(px_l * 36 + g * 9 + p) * 4];
        int off = __float_as_int(rec.x);
        float fx = rec.y, fy = rec.z, m = rec.w;
        float w11 = fx * fy;
        float w10 = fx - w11;
        float w01 = fy - w11;
        float w00 = 1.f - fx - fy + w11;
        w00 *= m; w10 *= m; w01 *= m; w11 *= m;
        v4h h0 = *(const v4h*)&base[off];
        v4h h1 = *(const v4h*)&base[off + CH];
        v4h h2 = *(const v4h*)&base[off + GP2 * CH];
        v4h h3 = *(const v4h*)&base[off + GP2 * CH + CH];
        a0 += w00*(float)h0[0] + w10*(float)h1[0] + w01*(float)h2[0] + w11*(float)h3[0];
        a1 += w00*(float)h0[1] + w10*(float)h1[1] + w01*(float)h2[1] + w11*(float)h3[1];
        a2 += w00*(float)h0[2] + w10*(float)h1[2] + w01*(float)h2[2] + w11*(float)h3[2];
        a3 += w00*(float)h0[3] + w10*(float)h1[3] + w01*(float)h2[3] + w11*(float)h3[3];
    }
    v4h res = { (_Float16)a0, (_Float16)a1, (_Float16)a2, (_Float16)a3 };
    *(v4h*)&core16[(size_t)pix * CH + c4] = res;
}

// ---- g4: out_proj via MFMA + NHWC->NCHW store ------------------------------
__global__ __launch_bounds__(512) void g4_outproj(const _Float16* __restrict__ core16,
                                                  const _Float16* __restrict__ wp,
                                                  const float* __restrict__ bias,
                                                  float* __restrict__ out) {
    __shared__ _Float16 a16[64 * ASTRIDE];
    __shared__ float res[128 * 68];                 // [c][w], stride 68
    int pix0 = blockIdx.x * 64;
    int t = threadIdx.x;
    const _Float16* src = core16 + (size_t)pix0 * CH;
    for (int q = t; q < 1024; q += 512)
        *(v8h*)&a16[(q >> 4) * ASTRIDE + (q & 15) * 8] = *(const v8h*)&src[q * 8];
    __syncthreads();
    int lane = t & 63, ncol = lane & 15;
    int ntb = ((t >> 6) & 1) * 4;
    v4f acc[4];
    #pragma unroll
    for (int j = 0; j < 4; j++) {
        float bv = bias[(ntb + j) * 16 + ncol];
        acc[j] = (v4f){bv, bv, bv, bv};
    }
    mfma_loop8(a16, wp, acc, t);
    int m0 = ((t >> 6) >> 1) * 16 + ((lane >> 4) * 4);
    #pragma unroll
    for (int j = 0; j < 4; j++)
        #pragma unroll
        for (int r = 0; r < 4; r++)
            res[((ntb + j) * 16 + ncol) * 68 + (m0 + r)] = acc[j][r];  // [c][w]
    __syncthreads();
    int b = pix0 >> 12, h = (pix0 >> 6) & 63;
    for (int q = t; q < 2048; q += 512) {
        int cc = q >> 4, w4 = (q & 15) * 4;
        float4 o = *(const float4*)&res[cc * 68 + w4];   // vector LDS read
        *(float4*)&out[(size_t)((b * CH + cc) * HH + h) * WWID + w4] = o;
    }
}

extern "C" void kernel_launch(void* const* d_in, const int* in_sizes, int n_in,
                              void* d_out, int out_size, void* d_ws, size_t ws_size,
                              hipStream_t stream) {
    const float* x        = (const float*)d_in[0];
    const float* conv_w   = (const float*)d_in[1];
    const float* conv_b   = (const float*)d_in[2];
    const float* in_proj_w= (const float*)d_in[3];
    const float* in_proj_b= (const float*)d_in[4];
    const float* dw_w     = (const float*)d_in[5];
    const float* dw_b     = (const float*)d_in[6];
    const float* ln_g     = (const float*)d_in[7];
    const float* ln_b     = (const float*)d_in[8];
    const float* off_w    = (const float*)d_in[9];
    const float* off_b    = (const float*)d_in[10];
    const float* mask_w   = (const float*)d_in[11];
    const float* mask_b   = (const float*)d_in[12];
    const float* out_proj_w = (const float*)d_in[13];
    const float* out_proj_b = (const float*)d_in[14];
    float* out = (float*)d_out;

    float* ws = (float*)d_ws;
    // float-offsets: wp | dwT | y16 | xpad16(70x70 guard) | core16 | tapmeta
    const size_t O_WP   = 0;
    const size_t O_DWT  = 32768;
    const size_t O_Y16  = 34816;                    // 2,097,152 floats (halfs)
    const size_t O_XP16 = O_Y16 + 2097152;          // 2,508,800 floats
    const size_t O_C16  = O_XP16 + 2508800;         // 2,097,152 floats
    const size_t O_TM   = O_C16 + 2097152;          // 4,718,592 floats
    _Float16* wp     = (_Float16*)(ws + O_WP);
    float*    dwT    = ws + O_DWT;
    _Float16* y16    = (_Float16*)(ws + O_Y16);
    _Float16* xpad16 = (_Float16*)(ws + O_XP16);
    _Float16* core16 = (_Float16*)(ws + O_C16);
    float*    tapmeta= ws + O_TM;

    _Float16* wp_conv = wp;
    _Float16* wp_in   = wp + (size_t)2048 * 8;
    _Float16* wp_om   = wp + (size_t)4096 * 8;
    _Float16* wp_out  = wp + (size_t)5888 * 8;

    p0_pack<<<64, 256, 0, stream>>>(conv_w, in_proj_w, off_w, mask_w, out_proj_w, dw_w, wp, dwT, xpad16);
    gA_conv_inproj<<<NPIX / 64, 512, 0, stream>>>(x, wp_conv, wp_in, conv_b, in_proj_b, y16, xpad16);
    gF_dwln_offmask<<<NPIX / 64, 512, 0, stream>>>(y16, wp_om, dwT, dw_b, ln_g, ln_b, off_b, mask_b, tapmeta);
    kD_gather<<<NPIX / 8, 256, 0, stream>>>(xpad16, tapmeta, core16);
    g4_outproj<<<NPIX / 64, 512, 0, stream>>>(core16, wp_out, out_proj_b, out);
}